// Round 1
// baseline (11841.803 us; speedup 1.0000x reference)
//
#include <hip/hip_runtime.h>

#define NNODES 50000
#define NEDGES 1600000
// IN_DIM = 128, N_HEADS = 8, OUT_DIM = 16, H*D = 128

// ---------------------------------------------------------------------------
// Fused QKV projection: C = state @ W + b for W in {WQ, WK, WV} (blockIdx.y).
// Classic SGEMM tile: 128x128 block tile, BK=8, 256 threads, 8x8 per thread.
// ---------------------------------------------------------------------------
__global__ __launch_bounds__(256) void proj_qkv(
    const float* __restrict__ state,
    const float* __restrict__ WQ, const float* __restrict__ bQ,
    const float* __restrict__ WK, const float* __restrict__ bK,
    const float* __restrict__ WV, const float* __restrict__ bV,
    float* __restrict__ Qo, float* __restrict__ Ko, float* __restrict__ Vo,
    int N)
{
    const float* W; const float* bias; float* C;
    if (blockIdx.y == 0)      { W = WQ; bias = bQ; C = Qo; }
    else if (blockIdx.y == 1) { W = WK; bias = bK; C = Ko; }
    else                      { W = WV; bias = bV; C = Vo; }

    __shared__ float As[8][128];   // [k][m]
    __shared__ float Bs[8][128];   // [k][n]

    const int tid = threadIdx.x;
    const int tx = tid & 15;       // output col group (col = tx + 16*j)
    const int ty = tid >> 4;       // output row group (row = ty + 16*i)
    const int m0 = blockIdx.x * 128;

    float acc[8][8];
#pragma unroll
    for (int i = 0; i < 8; ++i)
#pragma unroll
        for (int j = 0; j < 8; ++j) acc[i][j] = 0.f;

    const int arow = tid >> 1;          // 0..127
    const int ak   = (tid & 1) * 4;     // 0 or 4
    const int brow = tid >> 5;          // 0..7
    const int bcol = (tid & 31) * 4;    // 0..124
    const int grow = m0 + arow;

    for (int k0 = 0; k0 < 128; k0 += 8) {
        float4 av = make_float4(0.f, 0.f, 0.f, 0.f);
        if (grow < N) av = *(const float4*)(state + grow * 128 + k0 + ak);
        float4 bv = *(const float4*)(W + (k0 + brow) * 128 + bcol);
        __syncthreads();   // previous-iter readers done before we overwrite
        As[ak + 0][arow] = av.x;
        As[ak + 1][arow] = av.y;
        As[ak + 2][arow] = av.z;
        As[ak + 3][arow] = av.w;
        *(float4*)&Bs[brow][bcol] = bv;
        __syncthreads();
#pragma unroll
        for (int k = 0; k < 8; ++k) {
            float a[8], b[8];
#pragma unroll
            for (int i = 0; i < 8; ++i) a[i] = As[k][ty + 16 * i];
#pragma unroll
            for (int j = 0; j < 8; ++j) b[j] = Bs[k][tx + 16 * j];
#pragma unroll
            for (int i = 0; i < 8; ++i)
#pragma unroll
                for (int j = 0; j < 8; ++j)
                    acc[i][j] = fmaf(a[i], b[j], acc[i][j]);
        }
    }

    float bcache[8];
#pragma unroll
    for (int j = 0; j < 8; ++j) bcache[j] = bias[tx + 16 * j];
#pragma unroll
    for (int i = 0; i < 8; ++i) {
        const int row = m0 + ty + 16 * i;
        if (row < N) {
#pragma unroll
            for (int j = 0; j < 8; ++j)
                C[row * 128 + tx + 16 * j] = acc[i][j] + bcache[j];
        }
    }
}

// ---------------------------------------------------------------------------
// Edge kernel: one thread per (edge, head). score = exp(clip(K[s,h].Q[d,h]/4)),
// scatter wV += V[s,h]*score into out, z[d,h] += score.
// unsafeAtomicAdd -> hardware global_atomic_add_f32 (no CAS loop).
// ---------------------------------------------------------------------------
__global__ __launch_bounds__(256) void edge_kernel(
    const int* __restrict__ src, const int* __restrict__ dst,
    const float* __restrict__ Q, const float* __restrict__ K,
    const float* __restrict__ V,
    float* __restrict__ out, float* __restrict__ z)
{
    const int idx = blockIdx.x * 256 + threadIdx.x;
    if (idx >= NEDGES * 8) return;
    const int e = idx >> 3;
    const int h = idx & 7;
    const int s = src[e];
    const int d = dst[e];

    const float4* kp = (const float4*)(K + s * 128 + h * 16);
    const float4* qp = (const float4*)(Q + d * 128 + h * 16);
    const float4 k0 = kp[0], k1 = kp[1], k2 = kp[2], k3 = kp[3];
    const float4 q0 = qp[0], q1 = qp[1], q2 = qp[2], q3 = qp[3];

    float sdot = k0.x * q0.x + k0.y * q0.y + k0.z * q0.z + k0.w * q0.w
               + k1.x * q1.x + k1.y * q1.y + k1.z * q1.z + k1.w * q1.w
               + k2.x * q2.x + k2.y * q2.y + k2.z * q2.z + k2.w * q2.w
               + k3.x * q3.x + k3.y * q3.y + k3.z * q3.z + k3.w * q3.w;

    const float sc = fminf(fmaxf(sdot * 0.25f, -5.f), 5.f);
    const float w  = __expf(sc);

    const float4* vp = (const float4*)(V + s * 128 + h * 16);
    const float4 v0 = vp[0], v1 = vp[1], v2 = vp[2], v3 = vp[3];
    float* op = out + d * 128 + h * 16;

    unsafeAtomicAdd(op + 0,  v0.x * w);
    unsafeAtomicAdd(op + 1,  v0.y * w);
    unsafeAtomicAdd(op + 2,  v0.z * w);
    unsafeAtomicAdd(op + 3,  v0.w * w);
    unsafeAtomicAdd(op + 4,  v1.x * w);
    unsafeAtomicAdd(op + 5,  v1.y * w);
    unsafeAtomicAdd(op + 6,  v1.z * w);
    unsafeAtomicAdd(op + 7,  v1.w * w);
    unsafeAtomicAdd(op + 8,  v2.x * w);
    unsafeAtomicAdd(op + 9,  v2.y * w);
    unsafeAtomicAdd(op + 10, v2.z * w);
    unsafeAtomicAdd(op + 11, v2.w * w);
    unsafeAtomicAdd(op + 12, v3.x * w);
    unsafeAtomicAdd(op + 13, v3.y * w);
    unsafeAtomicAdd(op + 14, v3.z * w);
    unsafeAtomicAdd(op + 15, v3.w * w);
    unsafeAtomicAdd(z + d * 8 + h, w);
}

// ---------------------------------------------------------------------------
// Normalize: out[n,h,d] /= z[n,h].  idx>>4 == n*8+h exactly.
// ---------------------------------------------------------------------------
__global__ __launch_bounds__(256) void divide_kernel(
    float* __restrict__ out, const float* __restrict__ z)
{
    const int idx = blockIdx.x * 256 + threadIdx.x;
    if (idx >= NNODES * 128) return;
    out[idx] = out[idx] / z[idx >> 4];
}

extern "C" void kernel_launch(void* const* d_in, const int* in_sizes, int n_in,
                              void* d_out, int out_size, void* d_ws, size_t ws_size,
                              hipStream_t stream)
{
    const float* state = (const float*)d_in[0];
    const int*   src   = (const int*)d_in[1];
    const int*   dst   = (const int*)d_in[2];
    const float* WQ    = (const float*)d_in[3];
    const float* bQ    = (const float*)d_in[4];
    const float* WK    = (const float*)d_in[5];
    const float* bK    = (const float*)d_in[6];
    const float* WV    = (const float*)d_in[7];
    const float* bV    = (const float*)d_in[8];
    float* out = (float*)d_out;

    // workspace layout: Q | K | V | z   (3*50000*128 + 50000*8 floats = 78.4 MB)
    float* Q = (float*)d_ws;
    float* K = Q + (size_t)NNODES * 128;
    float* V = K + (size_t)NNODES * 128;
    float* z = V + (size_t)NNODES * 128;

    hipMemsetAsync(out, 0, (size_t)NNODES * 128 * sizeof(float), stream);
    hipMemsetAsync(z,   0, (size_t)NNODES * 8   * sizeof(float), stream);

    dim3 pgrid((NNODES + 127) / 128, 3);
    proj_qkv<<<pgrid, 256, 0, stream>>>(state, WQ, bQ, WK, bK, WV, bV,
                                        Q, K, V, NNODES);

    edge_kernel<<<(NEDGES * 8) / 256, 256, 0, stream>>>(src, dst, Q, K, V, out, z);

    divide_kernel<<<(NNODES * 128) / 256, 256, 0, stream>>>(out, z);
}

// Round 2
// 691.655 us; speedup vs baseline: 17.1210x; 17.1210x over previous
//
#include <hip/hip_runtime.h>

#define NNODES 50000
#define NEDGES 1600000
// IN_DIM = 128, N_HEADS = 8, OUT_DIM = 16, H*D = 128

// ---------------------------------------------------------------------------
// Fused QKV projection: C = state @ W + b for W in {WQ, WK, WV} (blockIdx.y).
// Classic SGEMM tile: 128x128 block tile, BK=8, 256 threads, 8x8 per thread.
// ---------------------------------------------------------------------------
__global__ __launch_bounds__(256) void proj_qkv(
    const float* __restrict__ state,
    const float* __restrict__ WQ, const float* __restrict__ bQ,
    const float* __restrict__ WK, const float* __restrict__ bK,
    const float* __restrict__ WV, const float* __restrict__ bV,
    float* __restrict__ Qo, float* __restrict__ Ko, float* __restrict__ Vo,
    int N)
{
    const float* W; const float* bias; float* C;
    if (blockIdx.y == 0)      { W = WQ; bias = bQ; C = Qo; }
    else if (blockIdx.y == 1) { W = WK; bias = bK; C = Ko; }
    else                      { W = WV; bias = bV; C = Vo; }

    __shared__ float As[8][128];   // [k][m]
    __shared__ float Bs[8][128];   // [k][n]

    const int tid = threadIdx.x;
    const int tx = tid & 15;       // output col group (col = tx + 16*j)
    const int ty = tid >> 4;       // output row group (row = ty + 16*i)
    const int m0 = blockIdx.x * 128;

    float acc[8][8];
#pragma unroll
    for (int i = 0; i < 8; ++i)
#pragma unroll
        for (int j = 0; j < 8; ++j) acc[i][j] = 0.f;

    const int arow = tid >> 1;          // 0..127
    const int ak   = (tid & 1) * 4;     // 0 or 4
    const int brow = tid >> 5;          // 0..7
    const int bcol = (tid & 31) * 4;    // 0..124
    const int grow = m0 + arow;

    for (int k0 = 0; k0 < 128; k0 += 8) {
        float4 av = make_float4(0.f, 0.f, 0.f, 0.f);
        if (grow < N) av = *(const float4*)(state + grow * 128 + k0 + ak);
        float4 bv = *(const float4*)(W + (k0 + brow) * 128 + bcol);
        __syncthreads();   // previous-iter readers done before we overwrite
        As[ak + 0][arow] = av.x;
        As[ak + 1][arow] = av.y;
        As[ak + 2][arow] = av.z;
        As[ak + 3][arow] = av.w;
        *(float4*)&Bs[brow][bcol] = bv;
        __syncthreads();
#pragma unroll
        for (int k = 0; k < 8; ++k) {
            float a[8], b[8];
#pragma unroll
            for (int i = 0; i < 8; ++i) a[i] = As[k][ty + 16 * i];
#pragma unroll
            for (int j = 0; j < 8; ++j) b[j] = Bs[k][tx + 16 * j];
#pragma unroll
            for (int i = 0; i < 8; ++i)
#pragma unroll
                for (int j = 0; j < 8; ++j)
                    acc[i][j] = fmaf(a[i], b[j], acc[i][j]);
        }
    }

    float bcache[8];
#pragma unroll
    for (int j = 0; j < 8; ++j) bcache[j] = bias[tx + 16 * j];
#pragma unroll
    for (int i = 0; i < 8; ++i) {
        const int row = m0 + ty + 16 * i;
        if (row < N) {
#pragma unroll
            for (int j = 0; j < 8; ++j)
                C[row * 128 + tx + 16 * j] = acc[i][j] + bcache[j];
        }
    }
}

// ---------------------------------------------------------------------------
// CSR build step 1: in-degree histogram.
// ---------------------------------------------------------------------------
__global__ __launch_bounds__(256) void hist_kernel(
    const int* __restrict__ dst, int* __restrict__ deg)
{
    const int e = blockIdx.x * 256 + threadIdx.x;
    if (e < NEDGES) atomicAdd(&deg[dst[e]], 1);
}

// ---------------------------------------------------------------------------
// CSR build step 2: exclusive scan of deg -> offs[NNODES+1], plus cursor copy.
// Single 1024-thread block; each thread owns a 49-element chunk.
// ---------------------------------------------------------------------------
__global__ __launch_bounds__(1024) void scan_kernel(
    const int* __restrict__ deg, int* __restrict__ offs, int* __restrict__ cursor)
{
    __shared__ int part[1024];
    const int t = threadIdx.x;
    const int CH = (NNODES + 1023) / 1024;   // 49
    const int base = t * CH;

    int sum = 0;
    for (int j = 0; j < CH; ++j) {
        const int idx = base + j;
        if (idx < NNODES) sum += deg[idx];
    }
    part[t] = sum;
    __syncthreads();

    // Hillis-Steele inclusive scan over 1024 partials
    for (int off = 1; off < 1024; off <<= 1) {
        const int v = (t >= off) ? part[t - off] : 0;
        __syncthreads();
        part[t] += v;
        __syncthreads();
    }

    int run = (t == 0) ? 0 : part[t - 1];    // exclusive prefix of this chunk
    for (int j = 0; j < CH; ++j) {
        const int idx = base + j;
        if (idx < NNODES) {
            offs[idx]   = run;
            cursor[idx] = run;
            run += deg[idx];
        }
    }
    if (t == 1023) offs[NNODES] = part[1023];
}

// ---------------------------------------------------------------------------
// CSR build step 3: scatter src ids into per-dst edge lists.
// ---------------------------------------------------------------------------
__global__ __launch_bounds__(256) void scatter_kernel(
    const int* __restrict__ src, const int* __restrict__ dst,
    int* __restrict__ cursor, int* __restrict__ eidx)
{
    const int e = blockIdx.x * 256 + threadIdx.x;
    if (e < NEDGES) {
        const int pos = atomicAdd(&cursor[dst[e]], 1);
        eidx[pos] = src[e];
    }
}

// ---------------------------------------------------------------------------
// Gather-side aggregation: one 128-thread block per dst node.
// Thread = (head h = tid>>4, dim d = tid&15). Q row in register; loop over
// incoming edges: coalesced K/V row loads, 16-lane shfl_xor dot-reduce,
// exp(clip), FMA accumulate. Zero atomics; one coalesced write per node.
// ---------------------------------------------------------------------------
__global__ __launch_bounds__(128) void aggregate_kernel(
    const int* __restrict__ eidx, const int* __restrict__ offs,
    const float* __restrict__ Q, const float* __restrict__ K,
    const float* __restrict__ V, float* __restrict__ out)
{
    const int n   = blockIdx.x;
    const int tid = threadIdx.x;

    const float qv = Q[n * 128 + tid];
    const int beg = offs[n];
    const int end = offs[n + 1];

    float acc = 0.f, zsum = 0.f;

    int i = beg;
    for (; i + 1 < end; i += 2) {            // 2-way unroll for load ILP
        const int s0 = eidx[i];
        const int s1 = eidx[i + 1];
        const float kv0 = K[s0 * 128 + tid];
        const float kv1 = K[s1 * 128 + tid];
        const float vv0 = V[s0 * 128 + tid];
        const float vv1 = V[s1 * 128 + tid];

        float p0 = kv0 * qv;
        p0 += __shfl_xor(p0, 1); p0 += __shfl_xor(p0, 2);
        p0 += __shfl_xor(p0, 4); p0 += __shfl_xor(p0, 8);
        float p1 = kv1 * qv;
        p1 += __shfl_xor(p1, 1); p1 += __shfl_xor(p1, 2);
        p1 += __shfl_xor(p1, 4); p1 += __shfl_xor(p1, 8);

        const float w0 = __expf(fminf(fmaxf(p0 * 0.25f, -5.f), 5.f));
        const float w1 = __expf(fminf(fmaxf(p1 * 0.25f, -5.f), 5.f));
        zsum += w0 + w1;
        acc = fmaf(vv0, w0, acc);
        acc = fmaf(vv1, w1, acc);
    }
    if (i < end) {
        const int s0 = eidx[i];
        const float kv0 = K[s0 * 128 + tid];
        const float vv0 = V[s0 * 128 + tid];
        float p0 = kv0 * qv;
        p0 += __shfl_xor(p0, 1); p0 += __shfl_xor(p0, 2);
        p0 += __shfl_xor(p0, 4); p0 += __shfl_xor(p0, 8);
        const float w0 = __expf(fminf(fmaxf(p0 * 0.25f, -5.f), 5.f));
        zsum += w0;
        acc = fmaf(vv0, w0, acc);
    }

    out[n * 128 + tid] = acc / zsum;
}

extern "C" void kernel_launch(void* const* d_in, const int* in_sizes, int n_in,
                              void* d_out, int out_size, void* d_ws, size_t ws_size,
                              hipStream_t stream)
{
    const float* state = (const float*)d_in[0];
    const int*   src   = (const int*)d_in[1];
    const int*   dst   = (const int*)d_in[2];
    const float* WQ    = (const float*)d_in[3];
    const float* bQ    = (const float*)d_in[4];
    const float* WK    = (const float*)d_in[5];
    const float* bK    = (const float*)d_in[6];
    const float* WV    = (const float*)d_in[7];
    const float* bV    = (const float*)d_in[8];
    float* out = (float*)d_out;

    // Workspace layout:
    //   Q, K, V        : 3 * 50000*128 floats          (76.8 MB)
    //   deg            : 50000 int
    //   offs           : 50001 int
    //   cursor         : 50000 int
    //   eidx           : 1600000 int                    (6.4 MB)
    float* Q = (float*)d_ws;
    float* K = Q + (size_t)NNODES * 128;
    float* V = K + (size_t)NNODES * 128;
    int* deg    = (int*)(V + (size_t)NNODES * 128);
    int* offs   = deg + NNODES;
    int* cursor = offs + (NNODES + 1);
    int* eidx   = cursor + NNODES;

    hipMemsetAsync(deg, 0, NNODES * sizeof(int), stream);

    dim3 pgrid((NNODES + 127) / 128, 3);
    proj_qkv<<<pgrid, 256, 0, stream>>>(state, WQ, bQ, WK, bK, WV, bV,
                                        Q, K, V, NNODES);

    const int eblocks = (NEDGES + 255) / 256;
    hist_kernel<<<eblocks, 256, 0, stream>>>(dst, deg);
    scan_kernel<<<1, 1024, 0, stream>>>(deg, offs, cursor);
    scatter_kernel<<<eblocks, 256, 0, stream>>>(src, dst, cursor, eidx);

    aggregate_kernel<<<NNODES, 128, 0, stream>>>(eidx, offs, Q, K, V, out);
}

// Round 3
// 472.676 us; speedup vs baseline: 25.0527x; 1.4633x over previous
//
#include <hip/hip_runtime.h>

#define NNODES 50000
#define NEDGES 1600000
// IN_DIM = 128, N_HEADS = 8, OUT_DIM = 16, H*D = 128

typedef __attribute__((ext_vector_type(8))) short short8;   // 8 x bf16 (MFMA A/B frag)
typedef __attribute__((ext_vector_type(4))) float fp32x4;   // MFMA C/D frag

__device__ __forceinline__ unsigned short f2bf(float f) {   // RNE fp32 -> bf16
    unsigned int u = __float_as_uint(f);
    u += 0x7fffu + ((u >> 16) & 1u);
    return (unsigned short)(u >> 16);
}
__device__ __forceinline__ float bflo(unsigned int p) { return __uint_as_float(p << 16); }
__device__ __forceinline__ float bfhi(unsigned int p) { return __uint_as_float(p & 0xffff0000u); }

// ---------------------------------------------------------------------------
// Cast state fp32 -> bf16 (8 elems/thread).
// ---------------------------------------------------------------------------
__global__ __launch_bounds__(256) void cast_state(
    const float* __restrict__ s, unsigned short* __restrict__ o)
{
    const int i = (blockIdx.x * 256 + threadIdx.x) * 8;
    if (i >= NNODES * 128) return;
    const float4 a = *(const float4*)(s + i);
    const float4 b = *(const float4*)(s + i + 4);
    short8 r;
    r[0] = (short)f2bf(a.x); r[1] = (short)f2bf(a.y);
    r[2] = (short)f2bf(a.z); r[3] = (short)f2bf(a.w);
    r[4] = (short)f2bf(b.x); r[5] = (short)f2bf(b.y);
    r[6] = (short)f2bf(b.z); r[7] = (short)f2bf(b.w);
    *(short8*)(o + i) = r;
}

// ---------------------------------------------------------------------------
// Cast + transpose W (128x128 fp32, k-major) -> WT bf16 (n-major): WT[n][k]=W[k][n]
// grid: 3*128 blocks of 128 threads; block = (w, n-row of WT), thread = k.
// ---------------------------------------------------------------------------
__global__ __launch_bounds__(128) void cast_wt(
    const float* __restrict__ WQ, const float* __restrict__ WK,
    const float* __restrict__ WV, unsigned short* __restrict__ WT)
{
    const int w = blockIdx.x >> 7;
    const int n = blockIdx.x & 127;
    const int k = threadIdx.x;
    const float* W = (w == 0) ? WQ : ((w == 1) ? WK : WV);
    WT[w * 16384 + n * 128 + k] = f2bf(W[k * 128 + n]);
}

// ---------------------------------------------------------------------------
// Fused QKV projection, bf16 MFMA 16x16x32. Block = 256 thr = 4 waves; wave w
// computes rows [blk*64+w*16, +16) x 128 cols for ALL THREE outputs (A-frag
// reused 3x). Epilogue: bias add + LDS transpose (stride 132) -> coalesced
// bf16x8 global stores.
// ---------------------------------------------------------------------------
__global__ __launch_bounds__(256) void proj_mfma(
    const unsigned short* __restrict__ Sb, const unsigned short* __restrict__ WT,
    const float* __restrict__ bQ, const float* __restrict__ bK,
    const float* __restrict__ bV,
    unsigned short* __restrict__ Qb, unsigned short* __restrict__ Kb,
    unsigned short* __restrict__ Vb)
{
    __shared__ float lbuf[4][16 * 132];

    const int tid  = threadIdx.x;
    const int wv   = tid >> 6;
    const int lane = tid & 63;
    const int lm   = lane & 15;    // A row / B col / C col within tile
    const int quad = lane >> 4;    // k-chunk select, C row group
    const int m0   = blockIdx.x * 64 + wv * 16;
    const int m    = m0 + lm;

    fp32x4 acc[3][8];
#pragma unroll
    for (int w = 0; w < 3; ++w)
#pragma unroll
        for (int t = 0; t < 8; ++t)
            acc[w][t] = (fp32x4){0.f, 0.f, 0.f, 0.f};

    const int kq = quad * 8;
#pragma unroll
    for (int kb = 0; kb < 128; kb += 32) {
        short8 a = (short8){0,0,0,0,0,0,0,0};
        if (m < NNODES) a = *(const short8*)(Sb + (size_t)m * 128 + kb + kq);
#pragma unroll
        for (int w = 0; w < 3; ++w) {
#pragma unroll
            for (int t = 0; t < 8; ++t) {
                const short8 b = *(const short8*)(WT + w * 16384 + (t * 16 + lm) * 128 + kb + kq);
                acc[w][t] = __builtin_amdgcn_mfma_f32_16x16x32_bf16(a, b, acc[w][t], 0, 0, 0);
            }
        }
    }

    // epilogue: per output, bias-add -> LDS (per-wave region) -> transposed read
    const int rrow = lane >> 2;          // 0..15
    const int rcol = (lane & 3) * 32;    // 0,32,64,96
    const int grow = m0 + rrow;
#pragma unroll
    for (int w = 0; w < 3; ++w) {
        const float* bp = (w == 0) ? bQ : ((w == 1) ? bK : bV);
        unsigned short* op = (w == 0) ? Qb : ((w == 1) ? Kb : Vb);
        float* L = &lbuf[wv][0];
#pragma unroll
        for (int t = 0; t < 8; ++t) {
            const float bb = bp[t * 16 + lm];
#pragma unroll
            for (int r = 0; r < 4; ++r)
                L[(quad * 4 + r) * 132 + t * 16 + lm] = acc[w][t][r] + bb;
        }
        __syncthreads();
        if (grow < NNODES) {
            unsigned short* gp = op + (size_t)grow * 128 + rcol;
#pragma unroll
            for (int c = 0; c < 4; ++c) {
                const float* lp = &L[rrow * 132 + rcol + c * 8];
                short8 r;
#pragma unroll
                for (int j = 0; j < 8; ++j) r[j] = (short)f2bf(lp[j]);
                *(short8*)(gp + c * 8) = r;
            }
        }
        __syncthreads();
    }
}

// ---------------------------------------------------------------------------
// CSR build: histogram (int4-vectorized).
// ---------------------------------------------------------------------------
__global__ __launch_bounds__(256) void hist_kernel(
    const int* __restrict__ dst, int* __restrict__ deg)
{
    const int e4 = (blockIdx.x * 256 + threadIdx.x) * 4;
    if (e4 >= NEDGES) return;
    const int4 d = *(const int4*)(dst + e4);
    atomicAdd(&deg[d.x], 1);
    atomicAdd(&deg[d.y], 1);
    atomicAdd(&deg[d.z], 1);
    atomicAdd(&deg[d.w], 1);
}

// ---------------------------------------------------------------------------
// 3-phase scan: A) per-block sums  B) scan block sums  C) intra-block scan+base
// ---------------------------------------------------------------------------
#define SCAN_BLOCKS ((NNODES + 255) / 256)   // 196

__global__ __launch_bounds__(256) void scanA(
    const int* __restrict__ deg, int* __restrict__ bsum)
{
    const int idx = blockIdx.x * 256 + threadIdx.x;
    int v = (idx < NNODES) ? deg[idx] : 0;
#pragma unroll
    for (int off = 32; off >= 1; off >>= 1) v += __shfl_down(v, off);
    __shared__ int ws_[4];
    if ((threadIdx.x & 63) == 0) ws_[threadIdx.x >> 6] = v;
    __syncthreads();
    if (threadIdx.x == 0) bsum[blockIdx.x] = ws_[0] + ws_[1] + ws_[2] + ws_[3];
}

__global__ __launch_bounds__(256) void scanB(
    const int* __restrict__ bsum, int* __restrict__ bbase, int* __restrict__ offs)
{
    __shared__ int sh[256];
    const int t = threadIdx.x;
    const int v = (t < SCAN_BLOCKS) ? bsum[t] : 0;
    sh[t] = v;
    __syncthreads();
    for (int off = 1; off < 256; off <<= 1) {
        const int tmp = (t >= off) ? sh[t - off] : 0;
        __syncthreads();
        sh[t] += tmp;
        __syncthreads();
    }
    if (t < SCAN_BLOCKS) bbase[t] = sh[t] - v;
    if (t == 255) offs[NNODES] = sh[255];
}

__global__ __launch_bounds__(256) void scanC(
    const int* __restrict__ deg, const int* __restrict__ bbase,
    int* __restrict__ offs, int* __restrict__ cursor)
{
    __shared__ int sh[256];
    const int t = threadIdx.x;
    const int idx = blockIdx.x * 256 + t;
    const int v = (idx < NNODES) ? deg[idx] : 0;
    sh[t] = v;
    __syncthreads();
    for (int off = 1; off < 256; off <<= 1) {
        const int tmp = (t >= off) ? sh[t - off] : 0;
        __syncthreads();
        sh[t] += tmp;
        __syncthreads();
    }
    if (idx < NNODES) {
        const int g = bbase[blockIdx.x] + sh[t] - v;
        offs[idx] = g;
        cursor[idx] = g;
    }
}

// ---------------------------------------------------------------------------
// Scatter src ids into per-dst edge lists (int4-vectorized).
// ---------------------------------------------------------------------------
__global__ __launch_bounds__(256) void scatter_kernel(
    const int* __restrict__ src, const int* __restrict__ dst,
    int* __restrict__ cursor, int* __restrict__ eidx)
{
    const int e4 = (blockIdx.x * 256 + threadIdx.x) * 4;
    if (e4 >= NEDGES) return;
    const int4 d = *(const int4*)(dst + e4);
    const int4 s = *(const int4*)(src + e4);
    eidx[atomicAdd(&cursor[d.x], 1)] = s.x;
    eidx[atomicAdd(&cursor[d.y], 1)] = s.y;
    eidx[atomicAdd(&cursor[d.z], 1)] = s.z;
    eidx[atomicAdd(&cursor[d.w], 1)] = s.w;
}

// ---------------------------------------------------------------------------
// Aggregation: one wave (64 lanes) per dst node; lane = 2 dims (elements
// 2l, 2l+1). bf16 ushort2 loads (4B/lane = 256B/wave row). 3-step shfl_xor
// dot-reduce within 8-lane head groups. Zero atomics; fused normalize.
// ---------------------------------------------------------------------------
__global__ __launch_bounds__(256) void aggregate_kernel(
    const int* __restrict__ eidx, const int* __restrict__ offs,
    const unsigned short* __restrict__ Qb, const unsigned short* __restrict__ Kb,
    const unsigned short* __restrict__ Vb, float* __restrict__ out)
{
    const int n = blockIdx.x * 4 + (threadIdx.x >> 6);
    const int l = threadIdx.x & 63;
    if (n >= NNODES) return;

    const unsigned int qp = *(const unsigned int*)(Qb + (size_t)n * 128 + 2 * l);
    const float q0 = bflo(qp), q1 = bfhi(qp);

    const int beg = offs[n];
    const int end = offs[n + 1];

    float a0 = 0.f, a1 = 0.f, z = 0.f;
    int i = beg;
    for (; i + 1 < end; i += 2) {
        const int s0 = eidx[i];
        const int s1 = eidx[i + 1];
        const unsigned int k0 = *(const unsigned int*)(Kb + (size_t)s0 * 128 + 2 * l);
        const unsigned int k1 = *(const unsigned int*)(Kb + (size_t)s1 * 128 + 2 * l);
        const unsigned int v0 = *(const unsigned int*)(Vb + (size_t)s0 * 128 + 2 * l);
        const unsigned int v1 = *(const unsigned int*)(Vb + (size_t)s1 * 128 + 2 * l);

        float p0 = fmaf(bfhi(k0), q1, bflo(k0) * q0);
        p0 += __shfl_xor(p0, 1); p0 += __shfl_xor(p0, 2); p0 += __shfl_xor(p0, 4);
        float p1 = fmaf(bfhi(k1), q1, bflo(k1) * q0);
        p1 += __shfl_xor(p1, 1); p1 += __shfl_xor(p1, 2); p1 += __shfl_xor(p1, 4);

        const float w0 = __expf(fminf(fmaxf(p0 * 0.25f, -5.f), 5.f));
        const float w1 = __expf(fminf(fmaxf(p1 * 0.25f, -5.f), 5.f));
        z += w0 + w1;
        a0 = fmaf(bflo(v0), w0, a0); a1 = fmaf(bfhi(v0), w0, a1);
        a0 = fmaf(bflo(v1), w1, a0); a1 = fmaf(bfhi(v1), w1, a1);
    }
    if (i < end) {
        const int s0 = eidx[i];
        const unsigned int k0 = *(const unsigned int*)(Kb + (size_t)s0 * 128 + 2 * l);
        const unsigned int v0 = *(const unsigned int*)(Vb + (size_t)s0 * 128 + 2 * l);
        float p0 = fmaf(bfhi(k0), q1, bflo(k0) * q0);
        p0 += __shfl_xor(p0, 1); p0 += __shfl_xor(p0, 2); p0 += __shfl_xor(p0, 4);
        const float w0 = __expf(fminf(fmaxf(p0 * 0.25f, -5.f), 5.f));
        z += w0;
        a0 = fmaf(bflo(v0), w0, a0); a1 = fmaf(bfhi(v0), w0, a1);
    }

    const float inv = 1.0f / z;
    float2 r; r.x = a0 * inv; r.y = a1 * inv;
    *(float2*)(out + (size_t)n * 128 + 2 * l) = r;
}

extern "C" void kernel_launch(void* const* d_in, const int* in_sizes, int n_in,
                              void* d_out, int out_size, void* d_ws, size_t ws_size,
                              hipStream_t stream)
{
    const float* state = (const float*)d_in[0];
    const int*   src   = (const int*)d_in[1];
    const int*   dst   = (const int*)d_in[2];
    const float* WQ    = (const float*)d_in[3];
    const float* bQ    = (const float*)d_in[4];
    const float* WK    = (const float*)d_in[5];
    const float* bK    = (const float*)d_in[6];
    const float* WV    = (const float*)d_in[7];
    const float* bV    = (const float*)d_in[8];
    float* out = (float*)d_out;

    // Workspace layout (all 16B-aligned):
    unsigned short* Sb = (unsigned short*)d_ws;                 // 50000*128 bf16
    unsigned short* Qb = Sb + (size_t)NNODES * 128;
    unsigned short* Kb = Qb + (size_t)NNODES * 128;
    unsigned short* Vb = Kb + (size_t)NNODES * 128;
    unsigned short* WT = Vb + (size_t)NNODES * 128;             // 3*128*128 bf16
    int* deg    = (int*)(WT + 3 * 16384);
    int* bsum   = deg + NNODES;          // 256 (pad; 50000 is 16B-multiple count)
    int* bbase  = bsum + 256;
    int* offs   = bbase + 256;           // 50004 (padded)
    int* cursor = offs + 50004;
    int* eidx   = cursor + NNODES;       // 1600000

    hipMemsetAsync(deg, 0, NNODES * sizeof(int), stream);

    cast_state<<<(NNODES * 128 / 8 + 255) / 256, 256, 0, stream>>>(state, Sb);
    cast_wt<<<3 * 128, 128, 0, stream>>>(WQ, WK, WV, WT);
    proj_mfma<<<(NNODES + 63) / 64, 256, 0, stream>>>(Sb, WT, bQ, bK, bV, Qb, Kb, Vb);

    const int e4blocks = (NEDGES / 4 + 255) / 256;
    hist_kernel<<<e4blocks, 256, 0, stream>>>(dst, deg);
    scanA<<<SCAN_BLOCKS, 256, 0, stream>>>(deg, bsum);
    scanB<<<1, 256, 0, stream>>>(bsum, bbase, offs);
    scanC<<<SCAN_BLOCKS, 256, 0, stream>>>(deg, bbase, offs, cursor);
    scatter_kernel<<<e4blocks, 256, 0, stream>>>(src, dst, cursor, eidx);

    aggregate_kernel<<<(NNODES + 3) / 4, 256, 0, stream>>>(eidx, offs, Qb, Kb, Vb, out);
}

// Round 4
// 322.736 us; speedup vs baseline: 36.6919x; 1.4646x over previous
//
#include <hip/hip_runtime.h>

#define NNODES 50000
#define NEDGES 1600000
#define NB 196        // buckets = dst>>8  (50000/256 -> 0..195)
#define BCAP 10240    // edges per bucket capacity (mean 8163, +20 sigma)

typedef __attribute__((ext_vector_type(8))) short short8;   // 8 x bf16
typedef __attribute__((ext_vector_type(4))) float fp32x4;   // MFMA C/D frag

__device__ __forceinline__ unsigned short f2bf(float f) {   // RNE fp32 -> bf16
    unsigned int u = __float_as_uint(f);
    u += 0x7fffu + ((u >> 16) & 1u);
    return (unsigned short)(u >> 16);
}
__device__ __forceinline__ float bflo(unsigned int p) { return __uint_as_float(p << 16); }
__device__ __forceinline__ float bfhi(unsigned int p) { return __uint_as_float(p & 0xffff0000u); }

// ---------------------------------------------------------------------------
// Cast + transpose W (128x128 fp32, k-major) -> WT bf16 (n-major).
// ---------------------------------------------------------------------------
__global__ __launch_bounds__(128) void cast_wt(
    const float* __restrict__ WQ, const float* __restrict__ WK,
    const float* __restrict__ WV, unsigned short* __restrict__ WT)
{
    const int w = blockIdx.x >> 7;
    const int n = blockIdx.x & 127;
    const int k = threadIdx.x;
    const float* W = (w == 0) ? WQ : ((w == 1) ? WK : WV);
    WT[w * 16384 + n * 128 + k] = f2bf(W[k * 128 + n]);
}

// ---------------------------------------------------------------------------
// Fused QKV projection, bf16 MFMA 16x16x32, fp32 state read + in-register
// cast (cast_state kernel eliminated). Outputs: Qb [n][128] bf16 and KVb
// [n][256] bf16 with K in cols 0..127, V in cols 128..255 (interleaved for
// aggregate locality). Epilogue: bias add + LDS transpose -> coalesced stores.
// ---------------------------------------------------------------------------
__global__ __launch_bounds__(256) void proj_mfma(
    const float* __restrict__ state, const unsigned short* __restrict__ WT,
    const float* __restrict__ bQ, const float* __restrict__ bK,
    const float* __restrict__ bV,
    unsigned short* __restrict__ Qb, unsigned short* __restrict__ KVb)
{
    __shared__ float lbuf[4][16 * 132];

    const int tid  = threadIdx.x;
    const int wv   = tid >> 6;
    const int lane = tid & 63;
    const int lm   = lane & 15;    // A row / B col / C col within tile
    const int quad = lane >> 4;    // k-chunk select, C row group
    const int m0   = blockIdx.x * 64 + wv * 16;
    const int m    = m0 + lm;

    fp32x4 acc[3][8];
#pragma unroll
    for (int w = 0; w < 3; ++w)
#pragma unroll
        for (int t = 0; t < 8; ++t)
            acc[w][t] = (fp32x4){0.f, 0.f, 0.f, 0.f};

    const int kq = quad * 8;
#pragma unroll
    for (int kb = 0; kb < 128; kb += 32) {
        short8 a = (short8){0,0,0,0,0,0,0,0};
        if (m < NNODES) {
            const float4 f0 = *(const float4*)(state + (size_t)m * 128 + kb + kq);
            const float4 f1 = *(const float4*)(state + (size_t)m * 128 + kb + kq + 4);
            a[0] = (short)f2bf(f0.x); a[1] = (short)f2bf(f0.y);
            a[2] = (short)f2bf(f0.z); a[3] = (short)f2bf(f0.w);
            a[4] = (short)f2bf(f1.x); a[5] = (short)f2bf(f1.y);
            a[6] = (short)f2bf(f1.z); a[7] = (short)f2bf(f1.w);
        }
#pragma unroll
        for (int w = 0; w < 3; ++w) {
#pragma unroll
            for (int t = 0; t < 8; ++t) {
                const short8 b = *(const short8*)(WT + w * 16384 + (t * 16 + lm) * 128 + kb + kq);
                acc[w][t] = __builtin_amdgcn_mfma_f32_16x16x32_bf16(a, b, acc[w][t], 0, 0, 0);
            }
        }
    }

    const int rrow = lane >> 2;          // 0..15
    const int rcol = (lane & 3) * 32;    // 0,32,64,96
    const int grow = m0 + rrow;
#pragma unroll
    for (int w = 0; w < 3; ++w) {
        const float* bp = (w == 0) ? bQ : ((w == 1) ? bK : bV);
        float* L = &lbuf[wv][0];
#pragma unroll
        for (int t = 0; t < 8; ++t) {
            const float bb = bp[t * 16 + lm];
#pragma unroll
            for (int r = 0; r < 4; ++r)
                L[(quad * 4 + r) * 132 + t * 16 + lm] = acc[w][t][r] + bb;
        }
        __syncthreads();
        if (grow < NNODES) {
            unsigned short* gp;
            if (w == 0)      gp = Qb  + (size_t)grow * 128 + rcol;
            else if (w == 1) gp = KVb + (size_t)grow * 256 + rcol;
            else             gp = KVb + (size_t)grow * 256 + 128 + rcol;
#pragma unroll
            for (int c = 0; c < 4; ++c) {
                const float* lp = &L[rrow * 132 + rcol + c * 8];
                short8 r;
#pragma unroll
                for (int j = 0; j < 8; ++j) r[j] = (short)f2bf(lp[j]);
                *(short8*)(gp + c * 8) = r;
            }
        }
        __syncthreads();
    }
}

// ---------------------------------------------------------------------------
// Counting-sort pass 1: bucket edges by dst>>8. Per 1024-edge block: LDS
// histogram (196 bins) -> LDS scan -> one global atomic per touched bucket
// (~196/block vs 1024) -> in-LDS grouping -> bucket-grouped (mostly
// coalesced) global writes of packed (dst,src).
// ---------------------------------------------------------------------------
__global__ __launch_bounds__(256) void bucket_pass1(
    const int* __restrict__ src, const int* __restrict__ dst,
    int* __restrict__ gcur, unsigned long long* __restrict__ ebuf)
{
    __shared__ int hist[256];
    __shared__ int lofs[256];
    __shared__ int gbase[256];
    __shared__ int stot;
    __shared__ unsigned long long stage[1024];

    const int t = threadIdx.x;
    hist[t] = 0;
    __syncthreads();

    const long long e0 = (long long)blockIdx.x * 1024 + t * 4;
    const bool valid = (e0 < NEDGES);
    int4 s4, d4;
    int b[4], r[4];
    if (valid) {
        s4 = *(const int4*)(src + e0);
        d4 = *(const int4*)(dst + e0);
        b[0] = d4.x >> 8; b[1] = d4.y >> 8; b[2] = d4.z >> 8; b[3] = d4.w >> 8;
        r[0] = atomicAdd(&hist[b[0]], 1);
        r[1] = atomicAdd(&hist[b[1]], 1);
        r[2] = atomicAdd(&hist[b[2]], 1);
        r[3] = atomicAdd(&hist[b[3]], 1);
    }
    __syncthreads();

    // inclusive Hillis-Steele scan of hist into lofs
    const int v = hist[t];
    lofs[t] = v;
    __syncthreads();
    for (int off = 1; off < 256; off <<= 1) {
        const int y = (t >= off) ? lofs[t - off] : 0;
        __syncthreads();
        lofs[t] += y;
        __syncthreads();
    }
    if (t == 255) stot = lofs[255];
    if (t < NB && v > 0) gbase[t] = atomicAdd(&gcur[t], v);
    __syncthreads();
    lofs[t] -= v;                 // exclusive
    __syncthreads();

    if (valid) {
#pragma unroll
        for (int j = 0; j < 4; ++j) {
            const int ss = (j == 0) ? s4.x : ((j == 1) ? s4.y : ((j == 2) ? s4.z : s4.w));
            const int dd = (j == 0) ? d4.x : ((j == 1) ? d4.y : ((j == 2) ? d4.z : d4.w));
            stage[lofs[b[j]] + r[j]] =
                ((unsigned long long)(unsigned int)dd << 32) | (unsigned int)ss;
        }
    }
    __syncthreads();

    const int tot = stot;
#pragma unroll
    for (int j = 0; j < 4; ++j) {
        const int slot = t + 256 * j;
        if (slot < tot) {
            const unsigned long long e = stage[slot];
            const int bb = (int)(e >> 32) >> 8;
            const long long g = (long long)bb * BCAP + gbase[bb] + (slot - lofs[bb]);
            ebuf[g] = e;
        }
    }
}

// ---------------------------------------------------------------------------
// Counting-sort pass 2: one block per bucket. LDS histogram over the 256
// local nodes -> LDS scan -> per-node offsB/offsE (bucket-strided CSR, no
// global scan) -> in-LDS sort of src ids -> coalesced eidx write.
// ---------------------------------------------------------------------------
__global__ __launch_bounds__(256) void bucket_pass2(
    const unsigned long long* __restrict__ ebuf, const int* __restrict__ gcur,
    int* __restrict__ eidx, int* __restrict__ offsB, int* __restrict__ offsE)
{
    __shared__ int hist[256];
    __shared__ int lofs[256];
    __shared__ int cur[256];
    __shared__ int srcbuf[BCAP];    // 40 KB

    const int b = blockIdx.x;
    const int t = threadIdx.x;
    int cnt = gcur[b];
    if (cnt > BCAP) cnt = BCAP;     // safety clamp (never triggers)
    const long long base = (long long)b * BCAP;

    hist[t] = 0;
    __syncthreads();

    for (int i = t; i < cnt; i += 256) {
        const unsigned long long e = ebuf[base + i];
        atomicAdd(&hist[((int)(e >> 32)) & 255], 1);
    }
    __syncthreads();

    const int v = hist[t];
    lofs[t] = v;
    __syncthreads();
    for (int off = 1; off < 256; off <<= 1) {
        const int y = (t >= off) ? lofs[t - off] : 0;
        __syncthreads();
        lofs[t] += y;
        __syncthreads();
    }
    lofs[t] -= v;                   // exclusive
    __syncthreads();
    cur[t] = lofs[t];
    const int n = b * 256 + t;
    if (n < NNODES) {
        offsB[n] = (int)(base + lofs[t]);
        offsE[n] = (int)(base + lofs[t] + v);
    }
    __syncthreads();

    for (int i = t; i < cnt; i += 256) {
        const unsigned long long e = ebuf[base + i];
        const int p = atomicAdd(&cur[((int)(e >> 32)) & 255], 1);
        srcbuf[p] = (int)e;
    }
    __syncthreads();

    for (int i = t; i < cnt; i += 256)
        eidx[base + i] = srcbuf[i];
}

// ---------------------------------------------------------------------------
// Aggregation: one wave per dst node; lane = 2 dims. KV interleaved per node
// (one address chain, 512B locality per gathered edge). Zero atomics.
// ---------------------------------------------------------------------------
__global__ __launch_bounds__(256) void aggregate_kernel(
    const int* __restrict__ eidx, const int* __restrict__ offsB,
    const int* __restrict__ offsE,
    const unsigned short* __restrict__ Qb, const unsigned short* __restrict__ KVb,
    float* __restrict__ out)
{
    const int n = blockIdx.x * 4 + (threadIdx.x >> 6);
    const int l = threadIdx.x & 63;
    if (n >= NNODES) return;

    const unsigned int qp = *(const unsigned int*)(Qb + (size_t)n * 128 + 2 * l);
    const float q0 = bflo(qp), q1 = bfhi(qp);

    int i = offsB[n];
    const int end = offsE[n];

    float a0 = 0.f, a1 = 0.f, z = 0.f;
    for (; i + 1 < end; i += 2) {
        const int s0 = eidx[i];
        const int s1 = eidx[i + 1];
        const unsigned short* kv0 = KVb + (size_t)s0 * 256 + 2 * l;
        const unsigned short* kv1 = KVb + (size_t)s1 * 256 + 2 * l;
        const unsigned int k0 = *(const unsigned int*)(kv0);
        const unsigned int k1 = *(const unsigned int*)(kv1);
        const unsigned int v0 = *(const unsigned int*)(kv0 + 128);
        const unsigned int v1 = *(const unsigned int*)(kv1 + 128);

        float p0 = fmaf(bfhi(k0), q1, bflo(k0) * q0);
        p0 += __shfl_xor(p0, 1); p0 += __shfl_xor(p0, 2); p0 += __shfl_xor(p0, 4);
        float p1 = fmaf(bfhi(k1), q1, bflo(k1) * q0);
        p1 += __shfl_xor(p1, 1); p1 += __shfl_xor(p1, 2); p1 += __shfl_xor(p1, 4);

        const float w0 = __expf(fminf(fmaxf(p0 * 0.25f, -5.f), 5.f));
        const float w1 = __expf(fminf(fmaxf(p1 * 0.25f, -5.f), 5.f));
        z += w0 + w1;
        a0 = fmaf(bflo(v0), w0, a0); a1 = fmaf(bfhi(v0), w0, a1);
        a0 = fmaf(bflo(v1), w1, a0); a1 = fmaf(bfhi(v1), w1, a1);
    }
    if (i < end) {
        const int s0 = eidx[i];
        const unsigned short* kv0 = KVb + (size_t)s0 * 256 + 2 * l;
        const unsigned int k0 = *(const unsigned int*)(kv0);
        const unsigned int v0 = *(const unsigned int*)(kv0 + 128);
        float p0 = fmaf(bfhi(k0), q1, bflo(k0) * q0);
        p0 += __shfl_xor(p0, 1); p0 += __shfl_xor(p0, 2); p0 += __shfl_xor(p0, 4);
        const float w0 = __expf(fminf(fmaxf(p0 * 0.25f, -5.f), 5.f));
        z += w0;
        a0 = fmaf(bflo(v0), w0, a0); a1 = fmaf(bfhi(v0), w0, a1);
    }

    const float inv = 1.0f / z;
    float2 r; r.x = a0 * inv; r.y = a1 * inv;
    *(float2*)(out + (size_t)n * 128 + 2 * l) = r;
}

extern "C" void kernel_launch(void* const* d_in, const int* in_sizes, int n_in,
                              void* d_out, int out_size, void* d_ws, size_t ws_size,
                              hipStream_t stream)
{
    const float* state = (const float*)d_in[0];
    const int*   src   = (const int*)d_in[1];
    const int*   dst   = (const int*)d_in[2];
    const float* WQ    = (const float*)d_in[3];
    const float* bQ    = (const float*)d_in[4];
    const float* WK    = (const float*)d_in[5];
    const float* bK    = (const float*)d_in[6];
    const float* WV    = (const float*)d_in[7];
    const float* bV    = (const float*)d_in[8];
    float* out = (float*)d_out;

    // Workspace layout (16B-aligned boundaries):
    unsigned short* Qb  = (unsigned short*)d_ws;                 // 50000*128 bf16 = 12.8MB
    unsigned short* KVb = Qb + (size_t)NNODES * 128;             // 50000*256 bf16 = 25.6MB
    unsigned short* WT  = KVb + (size_t)NNODES * 256;            // 3*16384 bf16  = 96KB
    unsigned long long* ebuf = (unsigned long long*)(WT + 3 * 16384);  // NB*BCAP*8B = 16.1MB
    int* eidx  = (int*)(ebuf + (size_t)NB * BCAP);               // NB*BCAP*4B = 8.0MB
    int* gcur  = eidx + (size_t)NB * BCAP;                       // 196
    int* offsB = gcur + 256;                                     // 50000 (pad gcur to 256)
    int* offsE = offsB + NNODES;                                 // 50000

    hipMemsetAsync(gcur, 0, 256 * sizeof(int), stream);

    cast_wt<<<3 * 128, 128, 0, stream>>>(WQ, WK, WV, WT);
    proj_mfma<<<(NNODES + 63) / 64, 256, 0, stream>>>(state, WT, bQ, bK, bV, Qb, KVb);

    bucket_pass1<<<(NEDGES + 1023) / 1024, 256, 0, stream>>>(src, dst, gcur, ebuf);
    bucket_pass2<<<NB, 256, 0, stream>>>(ebuf, gcur, eidx, offsB, offsE);

    aggregate_kernel<<<(NNODES + 3) / 4, 256, 0, stream>>>(eidx, offsB, offsE, Qb, KVb, out);
}

// Round 5
// 309.152 us; speedup vs baseline: 38.3042x; 1.0439x over previous
//
#include <hip/hip_runtime.h>

#define NNODES 50000
#define NEDGES 1600000
#define NB 196        // buckets = dst>>8  (50000/256 -> 0..195)
#define BCAP 10240    // edges per bucket capacity (mean 8163, +20 sigma)

typedef __attribute__((ext_vector_type(8))) short short8;   // 8 x bf16
typedef __attribute__((ext_vector_type(4))) float fp32x4;   // MFMA C/D frag

__device__ __forceinline__ unsigned short f2bf(float f) {   // RNE fp32 -> bf16
    unsigned int u = __float_as_uint(f);
    u += 0x7fffu + ((u >> 16) & 1u);
    return (unsigned short)(u >> 16);
}
__device__ __forceinline__ float bflo(unsigned int p) { return __uint_as_float(p << 16); }
__device__ __forceinline__ float bfhi(unsigned int p) { return __uint_as_float(p & 0xffff0000u); }

// ---------------------------------------------------------------------------
// Cast + transpose W (128x128 fp32, k-major) -> WT bf16 (n-major).
// ---------------------------------------------------------------------------
__global__ __launch_bounds__(128) void cast_wt(
    const float* __restrict__ WQ, const float* __restrict__ WK,
    const float* __restrict__ WV, unsigned short* __restrict__ WT)
{
    const int w = blockIdx.x >> 7;
    const int n = blockIdx.x & 127;
    const int k = threadIdx.x;
    const float* W = (w == 0) ? WQ : ((w == 1) ? WK : WV);
    WT[w * 16384 + n * 128 + k] = f2bf(W[k * 128 + n]);
}

// ---------------------------------------------------------------------------
// Fused QKV projection, bf16 MFMA 16x16x32, fp32 state read + in-register
// cast. Outputs: Qb [n][128] bf16, KVb [n][256] bf16 (K cols 0..127, V cols
// 128..255). Epilogue: bias add + LDS transpose -> coalesced bf16x8 stores.
// ---------------------------------------------------------------------------
__global__ __launch_bounds__(256) void proj_mfma(
    const float* __restrict__ state, const unsigned short* __restrict__ WT,
    const float* __restrict__ bQ, const float* __restrict__ bK,
    const float* __restrict__ bV,
    unsigned short* __restrict__ Qb, unsigned short* __restrict__ KVb)
{
    __shared__ float lbuf[4][16 * 132];

    const int tid  = threadIdx.x;
    const int wv   = tid >> 6;
    const int lane = tid & 63;
    const int lm   = lane & 15;    // A row / B col / C col within tile
    const int quad = lane >> 4;    // k-chunk select, C row group
    const int m0   = blockIdx.x * 64 + wv * 16;
    const int m    = m0 + lm;

    fp32x4 acc[3][8];
#pragma unroll
    for (int w = 0; w < 3; ++w)
#pragma unroll
        for (int t = 0; t < 8; ++t)
            acc[w][t] = (fp32x4){0.f, 0.f, 0.f, 0.f};

    const int kq = quad * 8;
#pragma unroll
    for (int kb = 0; kb < 128; kb += 32) {
        short8 a = (short8){0,0,0,0,0,0,0,0};
        if (m < NNODES) {
            const float4 f0 = *(const float4*)(state + (size_t)m * 128 + kb + kq);
            const float4 f1 = *(const float4*)(state + (size_t)m * 128 + kb + kq + 4);
            a[0] = (short)f2bf(f0.x); a[1] = (short)f2bf(f0.y);
            a[2] = (short)f2bf(f0.z); a[3] = (short)f2bf(f0.w);
            a[4] = (short)f2bf(f1.x); a[5] = (short)f2bf(f1.y);
            a[6] = (short)f2bf(f1.z); a[7] = (short)f2bf(f1.w);
        }
#pragma unroll
        for (int w = 0; w < 3; ++w) {
#pragma unroll
            for (int t = 0; t < 8; ++t) {
                const short8 b = *(const short8*)(WT + w * 16384 + (t * 16 + lm) * 128 + kb + kq);
                acc[w][t] = __builtin_amdgcn_mfma_f32_16x16x32_bf16(a, b, acc[w][t], 0, 0, 0);
            }
        }
    }

    const int rrow = lane >> 2;          // 0..15
    const int rcol = (lane & 3) * 32;    // 0,32,64,96
    const int grow = m0 + rrow;
#pragma unroll
    for (int w = 0; w < 3; ++w) {
        const float* bp = (w == 0) ? bQ : ((w == 1) ? bK : bV);
        float* L = &lbuf[wv][0];
#pragma unroll
        for (int t = 0; t < 8; ++t) {
            const float bb = bp[t * 16 + lm];
#pragma unroll
            for (int r = 0; r < 4; ++r)
                L[(quad * 4 + r) * 132 + t * 16 + lm] = acc[w][t][r] + bb;
        }
        __syncthreads();
        if (grow < NNODES) {
            unsigned short* gp;
            if (w == 0)      gp = Qb  + (size_t)grow * 128 + rcol;
            else if (w == 1) gp = KVb + (size_t)grow * 256 + rcol;
            else             gp = KVb + (size_t)grow * 256 + 128 + rcol;
#pragma unroll
            for (int c = 0; c < 4; ++c) {
                const float* lp = &L[rrow * 132 + rcol + c * 8];   // 16B aligned
                const float4 x0 = *(const float4*)(lp);
                const float4 x1 = *(const float4*)(lp + 4);
                short8 r;
                r[0] = (short)f2bf(x0.x); r[1] = (short)f2bf(x0.y);
                r[2] = (short)f2bf(x0.z); r[3] = (short)f2bf(x0.w);
                r[4] = (short)f2bf(x1.x); r[5] = (short)f2bf(x1.y);
                r[6] = (short)f2bf(x1.z); r[7] = (short)f2bf(x1.w);
                *(short8*)(gp + c * 8) = r;
            }
        }
        __syncthreads();
    }
}

// ---------------------------------------------------------------------------
// Counting-sort pass 1: bucket edges by dst>>8 (LDS hist + scan + grouped
// writes; ~196 global atomics per 1024-edge block).
// ---------------------------------------------------------------------------
__global__ __launch_bounds__(256) void bucket_pass1(
    const int* __restrict__ src, const int* __restrict__ dst,
    int* __restrict__ gcur, unsigned long long* __restrict__ ebuf)
{
    __shared__ int hist[256];
    __shared__ int lofs[256];
    __shared__ int gbase[256];
    __shared__ int stot;
    __shared__ unsigned long long stage[1024];

    const int t = threadIdx.x;
    hist[t] = 0;
    __syncthreads();

    const long long e0 = (long long)blockIdx.x * 1024 + t * 4;
    const bool valid = (e0 < NEDGES);
    int4 s4, d4;
    int b[4], r[4];
    if (valid) {
        s4 = *(const int4*)(src + e0);
        d4 = *(const int4*)(dst + e0);
        b[0] = d4.x >> 8; b[1] = d4.y >> 8; b[2] = d4.z >> 8; b[3] = d4.w >> 8;
        r[0] = atomicAdd(&hist[b[0]], 1);
        r[1] = atomicAdd(&hist[b[1]], 1);
        r[2] = atomicAdd(&hist[b[2]], 1);
        r[3] = atomicAdd(&hist[b[3]], 1);
    }
    __syncthreads();

    const int v = hist[t];
    lofs[t] = v;
    __syncthreads();
    for (int off = 1; off < 256; off <<= 1) {
        const int y = (t >= off) ? lofs[t - off] : 0;
        __syncthreads();
        lofs[t] += y;
        __syncthreads();
    }
    if (t == 255) stot = lofs[255];
    if (t < NB && v > 0) gbase[t] = atomicAdd(&gcur[t], v);
    __syncthreads();
    lofs[t] -= v;                 // exclusive
    __syncthreads();

    if (valid) {
#pragma unroll
        for (int j = 0; j < 4; ++j) {
            const int ss = (j == 0) ? s4.x : ((j == 1) ? s4.y : ((j == 2) ? s4.z : s4.w));
            const int dd = (j == 0) ? d4.x : ((j == 1) ? d4.y : ((j == 2) ? d4.z : d4.w));
            stage[lofs[b[j]] + r[j]] =
                ((unsigned long long)(unsigned int)dd << 32) | (unsigned int)ss;
        }
    }
    __syncthreads();

    const int tot = stot;
#pragma unroll
    for (int j = 0; j < 4; ++j) {
        const int slot = t + 256 * j;
        if (slot < tot) {
            const unsigned long long e = stage[slot];
            const int bb = (int)(e >> 32) >> 8;
            const long long g = (long long)bb * BCAP + gbase[bb] + (slot - lofs[bb]);
            ebuf[g] = e;
        }
    }
}

// ---------------------------------------------------------------------------
// Counting-sort pass 2: one block per bucket; in-LDS per-node grouping,
// bucket-strided CSR (offsB/offsE), coalesced eidx write.
// ---------------------------------------------------------------------------
__global__ __launch_bounds__(256) void bucket_pass2(
    const unsigned long long* __restrict__ ebuf, const int* __restrict__ gcur,
    int* __restrict__ eidx, int* __restrict__ offsB, int* __restrict__ offsE)
{
    __shared__ int hist[256];
    __shared__ int lofs[256];
    __shared__ int cur[256];
    __shared__ int srcbuf[BCAP];    // 40 KB

    const int b = blockIdx.x;
    const int t = threadIdx.x;
    int cnt = gcur[b];
    if (cnt > BCAP) cnt = BCAP;
    const long long base = (long long)b * BCAP;

    hist[t] = 0;
    __syncthreads();

    for (int i = t; i < cnt; i += 256) {
        const unsigned long long e = ebuf[base + i];
        atomicAdd(&hist[((int)(e >> 32)) & 255], 1);
    }
    __syncthreads();

    const int v = hist[t];
    lofs[t] = v;
    __syncthreads();
    for (int off = 1; off < 256; off <<= 1) {
        const int y = (t >= off) ? lofs[t - off] : 0;
        __syncthreads();
        lofs[t] += y;
        __syncthreads();
    }
    lofs[t] -= v;                   // exclusive
    __syncthreads();
    cur[t] = lofs[t];
    const int n = b * 256 + t;
    if (n < NNODES) {
        offsB[n] = (int)(base + lofs[t]);
        offsE[n] = (int)(base + lofs[t] + v);
    }
    __syncthreads();

    for (int i = t; i < cnt; i += 256) {
        const unsigned long long e = ebuf[base + i];
        const int p = atomicAdd(&cur[((int)(e >> 32)) & 255], 1);
        srcbuf[p] = (int)e;
    }
    __syncthreads();

    for (int i = t; i < cnt; i += 256)
        eidx[base + i] = srcbuf[i];
}

// ---------------------------------------------------------------------------
// Aggregation: one wave per dst node; lane = (edge-slot eo=l>>3, head h=l&7).
// Each lane computes a FULL 16-dim head dot for its own edge via 2 dwordx4
// loads (32B/lane, coalesced across the 8 lanes of an edge). No per-edge
// shuffles; exp is 1 inst per 8 edges. V accumulates into 16 per-lane fp32
// partials; single cross-lane reduce per node; lanes 0..7 write float4 rows.
// ---------------------------------------------------------------------------
__global__ __launch_bounds__(256) void aggregate_kernel(
    const int* __restrict__ eidx, const int* __restrict__ offsB,
    const int* __restrict__ offsE,
    const unsigned short* __restrict__ Qb, const unsigned short* __restrict__ KVb,
    float* __restrict__ out)
{
    const int n = blockIdx.x * 4 + (threadIdx.x >> 6);
    const int l = threadIdx.x & 63;
    if (n >= NNODES) return;
    const int eo = l >> 3;       // edge slot 0..7
    const int h  = l & 7;        // head 0..7

    // Q[n][h*16 .. h*16+15] -> 16 fp32 regs
    const unsigned short* qp = Qb + (size_t)n * 128 + h * 16;
    const uint4 qa = *(const uint4*)(qp);
    const uint4 qc = *(const uint4*)(qp + 8);
    float q[16];
    q[0]  = bflo(qa.x); q[1]  = bfhi(qa.x); q[2]  = bflo(qa.y); q[3]  = bfhi(qa.y);
    q[4]  = bflo(qa.z); q[5]  = bfhi(qa.z); q[6]  = bflo(qa.w); q[7]  = bfhi(qa.w);
    q[8]  = bflo(qc.x); q[9]  = bfhi(qc.x); q[10] = bflo(qc.y); q[11] = bfhi(qc.y);
    q[12] = bflo(qc.z); q[13] = bfhi(qc.z); q[14] = bflo(qc.w); q[15] = bfhi(qc.w);

    const int beg = offsB[n];
    const int end = offsE[n];

    float acc[16];
#pragma unroll
    for (int j = 0; j < 16; ++j) acc[j] = 0.f;
    float zacc = 0.f;

#pragma unroll 2
    for (int i = beg; i < end; i += 8) {
        const int ei  = i + eo;
        const bool act = (ei < end);
        const int s = eidx[act ? ei : beg];
        const unsigned short* kp = KVb + (size_t)s * 256 + h * 16;
        const uint4 ka = *(const uint4*)(kp);
        const uint4 kc = *(const uint4*)(kp + 8);
        const uint4 va = *(const uint4*)(kp + 128);
        const uint4 vc = *(const uint4*)(kp + 136);

        float p;
        p = fmaf(bfhi(ka.x), q[1],  bflo(ka.x) * q[0]);
        p = fmaf(bflo(ka.y), q[2],  p); p = fmaf(bfhi(ka.y), q[3],  p);
        p = fmaf(bflo(ka.z), q[4],  p); p = fmaf(bfhi(ka.z), q[5],  p);
        p = fmaf(bflo(ka.w), q[6],  p); p = fmaf(bfhi(ka.w), q[7],  p);
        p = fmaf(bflo(kc.x), q[8],  p); p = fmaf(bfhi(kc.x), q[9],  p);
        p = fmaf(bflo(kc.y), q[10], p); p = fmaf(bfhi(kc.y), q[11], p);
        p = fmaf(bflo(kc.z), q[12], p); p = fmaf(bfhi(kc.z), q[13], p);
        p = fmaf(bflo(kc.w), q[14], p); p = fmaf(bfhi(kc.w), q[15], p);

        float w = __expf(fminf(fmaxf(p * 0.25f, -5.f), 5.f));
        w = act ? w : 0.f;
        zacc += w;

        acc[0]  = fmaf(bflo(va.x), w, acc[0]);  acc[1]  = fmaf(bfhi(va.x), w, acc[1]);
        acc[2]  = fmaf(bflo(va.y), w, acc[2]);  acc[3]  = fmaf(bfhi(va.y), w, acc[3]);
        acc[4]  = fmaf(bflo(va.z), w, acc[4]);  acc[5]  = fmaf(bfhi(va.z), w, acc[5]);
        acc[6]  = fmaf(bflo(va.w), w, acc[6]);  acc[7]  = fmaf(bfhi(va.w), w, acc[7]);
        acc[8]  = fmaf(bflo(vc.x), w, acc[8]);  acc[9]  = fmaf(bfhi(vc.x), w, acc[9]);
        acc[10] = fmaf(bflo(vc.y), w, acc[10]); acc[11] = fmaf(bfhi(vc.y), w, acc[11]);
        acc[12] = fmaf(bflo(vc.z), w, acc[12]); acc[13] = fmaf(bfhi(vc.z), w, acc[13]);
        acc[14] = fmaf(bflo(vc.w), w, acc[14]); acc[15] = fmaf(bfhi(vc.w), w, acc[15]);
    }

    // reduce across edge slots (lanes differing in bits 3..5)
#pragma unroll
    for (int st = 8; st < 64; st <<= 1) {
        zacc += __shfl_xor(zacc, st);
#pragma unroll
        for (int j = 0; j < 16; ++j) acc[j] += __shfl_xor(acc[j], st);
    }

    if (eo == 0) {
        const float inv = 1.0f / zacc;
        float* op = out + (size_t)n * 128 + h * 16;
        *(float4*)(op)      = make_float4(acc[0]*inv,  acc[1]*inv,  acc[2]*inv,  acc[3]*inv);
        *(float4*)(op + 4)  = make_float4(acc[4]*inv,  acc[5]*inv,  acc[6]*inv,  acc[7]*inv);
        *(float4*)(op + 8)  = make_float4(acc[8]*inv,  acc[9]*inv,  acc[10]*inv, acc[11]*inv);
        *(float4*)(op + 12) = make_float4(acc[12]*inv, acc[13]*inv, acc[14]*inv, acc[15]*inv);
    }
}

extern "C" void kernel_launch(void* const* d_in, const int* in_sizes, int n_in,
                              void* d_out, int out_size, void* d_ws, size_t ws_size,
                              hipStream_t stream)
{
    const float* state = (const float*)d_in[0];
    const int*   src   = (const int*)d_in[1];
    const int*   dst   = (const int*)d_in[2];
    const float* WQ    = (const float*)d_in[3];
    const float* bQ    = (const float*)d_in[4];
    const float* WK    = (const float*)d_in[5];
    const float* bK    = (const float*)d_in[6];
    const float* WV    = (const float*)d_in[7];
    const float* bV    = (const float*)d_in[8];
    float* out = (float*)d_out;

    unsigned short* Qb  = (unsigned short*)d_ws;                 // 50000*128 bf16
    unsigned short* KVb = Qb + (size_t)NNODES * 128;             // 50000*256 bf16
    unsigned short* WT  = KVb + (size_t)NNODES * 256;            // 3*16384 bf16
    unsigned long long* ebuf = (unsigned long long*)(WT + 3 * 16384);  // NB*BCAP*8B
    int* eidx  = (int*)(ebuf + (size_t)NB * BCAP);               // NB*BCAP*4B
    int* gcur  = eidx + (size_t)NB * BCAP;                       // 196 (pad 256)
    int* offsB = gcur + 256;                                     // 50000
    int* offsE = offsB + NNODES;                                 // 50000

    hipMemsetAsync(gcur, 0, 256 * sizeof(int), stream);

    cast_wt<<<3 * 128, 128, 0, stream>>>(WQ, WK, WV, WT);
    proj_mfma<<<(NNODES + 63) / 64, 256, 0, stream>>>(state, WT, bQ, bK, bV, Qb, KVb);

    bucket_pass1<<<(NEDGES + 1023) / 1024, 256, 0, stream>>>(src, dst, gcur, ebuf);
    bucket_pass2<<<NB, 256, 0, stream>>>(ebuf, gcur, eidx, offsB, offsE);

    aggregate_kernel<<<(NNODES + 3) / 4, 256, 0, stream>>>(eidx, offsB, offsE, Qb, KVb, out);
}

// Round 6
// 299.508 us; speedup vs baseline: 39.5376x; 1.0322x over previous
//
#include <hip/hip_runtime.h>

#define NNODES 50000
#define NEDGES 1600000
#define NB 196        // buckets = dst>>8  (50000/256 -> 0..195)
#define BCAP 10240    // edges per bucket capacity (mean 8163, +20 sigma)

typedef __attribute__((ext_vector_type(8))) short short8;   // 8 x bf16
typedef __attribute__((ext_vector_type(4))) float fp32x4;   // MFMA C/D frag

__device__ __forceinline__ unsigned short f2bf(float f) {   // RNE fp32 -> bf16
    unsigned int u = __float_as_uint(f);
    u += 0x7fffu + ((u >> 16) & 1u);
    return (unsigned short)(u >> 16);
}
__device__ __forceinline__ float bflo(unsigned int p) { return __uint_as_float(p << 16); }
__device__ __forceinline__ float bfhi(unsigned int p) { return __uint_as_float(p & 0xffff0000u); }

// ---------------------------------------------------------------------------
// Cast + transpose W (128x128 fp32, k-major) -> WT bf16 (n-major).
// Also zeroes gcur (replaces a memset dispatch; runs before pass1 in-stream).
// ---------------------------------------------------------------------------
__global__ __launch_bounds__(128) void cast_wt(
    const float* __restrict__ WQ, const float* __restrict__ WK,
    const float* __restrict__ WV, unsigned short* __restrict__ WT,
    int* __restrict__ gcur)
{
    if (blockIdx.x == 0) {
        gcur[threadIdx.x] = 0;
        gcur[threadIdx.x + 128] = 0;
    }
    const int w = blockIdx.x >> 7;
    const int n = blockIdx.x & 127;
    const int k = threadIdx.x;
    const float* W = (w == 0) ? WQ : ((w == 1) ? WK : WV);
    WT[w * 16384 + n * 128 + k] = f2bf(W[k * 128 + n]);
}

// ---------------------------------------------------------------------------
// Fused QKV projection, bf16 MFMA 16x16x32, fp32 state read + in-register
// cast. Outputs: Qb [n][128] bf16, KVb [n][256] bf16 (K cols 0..127, V cols
// 128..255). Epilogue: bias add + LDS transpose -> coalesced bf16x8 stores.
// ---------------------------------------------------------------------------
__global__ __launch_bounds__(256) void proj_mfma(
    const float* __restrict__ state, const unsigned short* __restrict__ WT,
    const float* __restrict__ bQ, const float* __restrict__ bK,
    const float* __restrict__ bV,
    unsigned short* __restrict__ Qb, unsigned short* __restrict__ KVb)
{
    __shared__ float lbuf[4][16 * 132];

    const int tid  = threadIdx.x;
    const int wv   = tid >> 6;
    const int lane = tid & 63;
    const int lm   = lane & 15;    // A row / B col / C col within tile
    const int quad = lane >> 4;    // k-chunk select, C row group
    const int m0   = blockIdx.x * 64 + wv * 16;
    const int m    = m0 + lm;

    fp32x4 acc[3][8];
#pragma unroll
    for (int w = 0; w < 3; ++w)
#pragma unroll
        for (int t = 0; t < 8; ++t)
            acc[w][t] = (fp32x4){0.f, 0.f, 0.f, 0.f};

    const int kq = quad * 8;
#pragma unroll
    for (int kb = 0; kb < 128; kb += 32) {
        short8 a = (short8){0,0,0,0,0,0,0,0};
        if (m < NNODES) {
            const float4 f0 = *(const float4*)(state + (size_t)m * 128 + kb + kq);
            const float4 f1 = *(const float4*)(state + (size_t)m * 128 + kb + kq + 4);
            a[0] = (short)f2bf(f0.x); a[1] = (short)f2bf(f0.y);
            a[2] = (short)f2bf(f0.z); a[3] = (short)f2bf(f0.w);
            a[4] = (short)f2bf(f1.x); a[5] = (short)f2bf(f1.y);
            a[6] = (short)f2bf(f1.z); a[7] = (short)f2bf(f1.w);
        }
#pragma unroll
        for (int w = 0; w < 3; ++w) {
#pragma unroll
            for (int t = 0; t < 8; ++t) {
                const short8 b = *(const short8*)(WT + w * 16384 + (t * 16 + lm) * 128 + kb + kq);
                acc[w][t] = __builtin_amdgcn_mfma_f32_16x16x32_bf16(a, b, acc[w][t], 0, 0, 0);
            }
        }
    }

    const int rrow = lane >> 2;          // 0..15
    const int rcol = (lane & 3) * 32;    // 0,32,64,96
    const int grow = m0 + rrow;
#pragma unroll
    for (int w = 0; w < 3; ++w) {
        const float* bp = (w == 0) ? bQ : ((w == 1) ? bK : bV);
        float* L = &lbuf[wv][0];
#pragma unroll
        for (int t = 0; t < 8; ++t) {
            const float bb = bp[t * 16 + lm];
#pragma unroll
            for (int r = 0; r < 4; ++r)
                L[(quad * 4 + r) * 132 + t * 16 + lm] = acc[w][t][r] + bb;
        }
        __syncthreads();
        if (grow < NNODES) {
            unsigned short* gp;
            if (w == 0)      gp = Qb  + (size_t)grow * 128 + rcol;
            else if (w == 1) gp = KVb + (size_t)grow * 256 + rcol;
            else             gp = KVb + (size_t)grow * 256 + 128 + rcol;
#pragma unroll
            for (int c = 0; c < 4; ++c) {
                const float* lp = &L[rrow * 132 + rcol + c * 8];   // 16B aligned
                const float4 x0 = *(const float4*)(lp);
                const float4 x1 = *(const float4*)(lp + 4);
                short8 r;
                r[0] = (short)f2bf(x0.x); r[1] = (short)f2bf(x0.y);
                r[2] = (short)f2bf(x0.z); r[3] = (short)f2bf(x0.w);
                r[4] = (short)f2bf(x1.x); r[5] = (short)f2bf(x1.y);
                r[6] = (short)f2bf(x1.z); r[7] = (short)f2bf(x1.w);
                *(short8*)(gp + c * 8) = r;
            }
        }
        __syncthreads();
    }
}

// ---------------------------------------------------------------------------
// Counting-sort pass 1: bucket edges by dst>>8. 2048 edges/block, SoA
// staging (dst,src separate), LDS hist + scan, ~<=196 global atomics/block,
// bucket-grouped coalesced-run writes into dbuf/sbuf.
// ---------------------------------------------------------------------------
__global__ __launch_bounds__(256) void bucket_pass1(
    const int* __restrict__ src, const int* __restrict__ dst,
    int* __restrict__ gcur, int* __restrict__ dbuf, int* __restrict__ sbuf)
{
    __shared__ int hist[256];
    __shared__ int lofs[256];
    __shared__ int gbase[256];
    __shared__ int stot;
    __shared__ int dstg[2048];
    __shared__ int srcg[2048];

    const int t = threadIdx.x;
    hist[t] = 0;
    __syncthreads();

    const long long e0 = (long long)blockIdx.x * 2048 + t * 8;
    const bool valid = (e0 < NEDGES);
    int4 sA, sB, dA, dB;
    int b[8], r[8];
    if (valid) {
        sA = *(const int4*)(src + e0);     sB = *(const int4*)(src + e0 + 4);
        dA = *(const int4*)(dst + e0);     dB = *(const int4*)(dst + e0 + 4);
        const int dd[8] = {dA.x, dA.y, dA.z, dA.w, dB.x, dB.y, dB.z, dB.w};
#pragma unroll
        for (int j = 0; j < 8; ++j) {
            b[j] = dd[j] >> 8;
            r[j] = atomicAdd(&hist[b[j]], 1);
        }
    }
    __syncthreads();

    const int v = hist[t];
    lofs[t] = v;
    __syncthreads();
    for (int off = 1; off < 256; off <<= 1) {
        const int y = (t >= off) ? lofs[t - off] : 0;
        __syncthreads();
        lofs[t] += y;
        __syncthreads();
    }
    if (t == 255) stot = lofs[255];
    if (t < NB && v > 0) gbase[t] = atomicAdd(&gcur[t], v);
    __syncthreads();
    lofs[t] -= v;                 // exclusive
    __syncthreads();

    if (valid) {
        const int dd[8] = {dA.x, dA.y, dA.z, dA.w, dB.x, dB.y, dB.z, dB.w};
        const int ss[8] = {sA.x, sA.y, sA.z, sA.w, sB.x, sB.y, sB.z, sB.w};
#pragma unroll
        for (int j = 0; j < 8; ++j) {
            const int p = lofs[b[j]] + r[j];
            dstg[p] = dd[j];
            srcg[p] = ss[j];
        }
    }
    __syncthreads();

    const int tot = stot;
#pragma unroll
    for (int j = 0; j < 8; ++j) {
        const int slot = t + 256 * j;
        if (slot < tot) {
            const int dd = dstg[slot];
            const int bb = dd >> 8;
            const long long g = (long long)bb * BCAP + gbase[bb] + (slot - lofs[bb]);
            dbuf[g] = dd;
            sbuf[g] = srcg[slot];
        }
    }
}

// ---------------------------------------------------------------------------
// Counting-sort pass 2: one block per bucket; LDS hist (reads dbuf only) +
// scan -> per-node offs2 (bucket-strided CSR), in-LDS grouping of src ids,
// coalesced eidx write.
// ---------------------------------------------------------------------------
__global__ __launch_bounds__(256) void bucket_pass2(
    const int* __restrict__ dbuf, const int* __restrict__ sbuf,
    const int* __restrict__ gcur, int* __restrict__ eidx, int2* __restrict__ offs2)
{
    __shared__ int hist[256];
    __shared__ int lofs[256];
    __shared__ int cur[256];
    __shared__ int srcbuf[BCAP];    // 40 KB

    const int b = blockIdx.x;
    const int t = threadIdx.x;
    int cnt = gcur[b];
    if (cnt > BCAP) cnt = BCAP;
    const long long base = (long long)b * BCAP;

    hist[t] = 0;
    __syncthreads();

    for (int i = t; i < cnt; i += 256)
        atomicAdd(&hist[dbuf[base + i] & 255], 1);
    __syncthreads();

    const int v = hist[t];
    lofs[t] = v;
    __syncthreads();
    for (int off = 1; off < 256; off <<= 1) {
        const int y = (t >= off) ? lofs[t - off] : 0;
        __syncthreads();
        lofs[t] += y;
        __syncthreads();
    }
    lofs[t] -= v;                   // exclusive
    __syncthreads();
    cur[t] = lofs[t];
    const int n = b * 256 + t;
    if (n < NNODES) {
        int2 oe; oe.x = (int)(base + lofs[t]); oe.y = (int)(base + lofs[t] + v);
        offs2[n] = oe;
    }
    __syncthreads();

    for (int i = t; i < cnt; i += 256) {
        const int d = dbuf[base + i] & 255;
        const int p = atomicAdd(&cur[d], 1);
        srcbuf[p] = sbuf[base + i];
    }
    __syncthreads();

    for (int i = t; i < cnt; i += 256)
        eidx[base + i] = srcbuf[i];
}

// ---------------------------------------------------------------------------
// Aggregation: one wave per dst node; lane = (edge-slot eo=l>>3, head h=l&7).
// 16 edges/iteration: 8 independent dwordx4 KV loads + 2 eidx loads issued
// before any use (explicit MLP — the round-5 kernel was latency-bound at
// unroll 2). Masked slots alias eidx[beg] (hot line, VALU-only waste).
// ---------------------------------------------------------------------------
__global__ __launch_bounds__(256) void aggregate_kernel(
    const int* __restrict__ eidx, const int2* __restrict__ offs2,
    const unsigned short* __restrict__ Qb, const unsigned short* __restrict__ KVb,
    float* __restrict__ out)
{
    const int n = blockIdx.x * 4 + (threadIdx.x >> 6);
    const int l = threadIdx.x & 63;
    if (n >= NNODES) return;
    const int eo = l >> 3;       // edge slot 0..7
    const int h  = l & 7;        // head 0..7

    const unsigned short* qp = Qb + (size_t)n * 128 + h * 16;
    const uint4 qa = *(const uint4*)(qp);
    const uint4 qc = *(const uint4*)(qp + 8);
    float q[16];
    q[0]  = bflo(qa.x); q[1]  = bfhi(qa.x); q[2]  = bflo(qa.y); q[3]  = bfhi(qa.y);
    q[4]  = bflo(qa.z); q[5]  = bfhi(qa.z); q[6]  = bflo(qa.w); q[7]  = bfhi(qa.w);
    q[8]  = bflo(qc.x); q[9]  = bfhi(qc.x); q[10] = bflo(qc.y); q[11] = bfhi(qc.y);
    q[12] = bflo(qc.z); q[13] = bfhi(qc.z); q[14] = bflo(qc.w); q[15] = bfhi(qc.w);

    const int2 oe = offs2[n];
    const int beg = oe.x, end = oe.y;

    float acc[16];
#pragma unroll
    for (int j = 0; j < 16; ++j) acc[j] = 0.f;
    float zacc = 0.f;

    for (int i = beg; i < end; i += 16) {
        const int ei0 = i + eo;
        const int ei1 = ei0 + 8;
        const bool act0 = (ei0 < end);
        const bool act1 = (ei1 < end);
        const int s0 = eidx[act0 ? ei0 : beg];
        const int s1 = eidx[act1 ? ei1 : beg];

        const unsigned short* kp0 = KVb + (size_t)s0 * 256 + h * 16;
        const unsigned short* kp1 = KVb + (size_t)s1 * 256 + h * 16;
        const uint4 ka0 = *(const uint4*)(kp0);
        const uint4 kc0 = *(const uint4*)(kp0 + 8);
        const uint4 va0 = *(const uint4*)(kp0 + 128);
        const uint4 vc0 = *(const uint4*)(kp0 + 136);
        const uint4 ka1 = *(const uint4*)(kp1);
        const uint4 kc1 = *(const uint4*)(kp1 + 8);
        const uint4 va1 = *(const uint4*)(kp1 + 128);
        const uint4 vc1 = *(const uint4*)(kp1 + 136);

        float p0;
        p0 = fmaf(bfhi(ka0.x), q[1],  bflo(ka0.x) * q[0]);
        p0 = fmaf(bflo(ka0.y), q[2],  p0); p0 = fmaf(bfhi(ka0.y), q[3],  p0);
        p0 = fmaf(bflo(ka0.z), q[4],  p0); p0 = fmaf(bfhi(ka0.z), q[5],  p0);
        p0 = fmaf(bflo(ka0.w), q[6],  p0); p0 = fmaf(bfhi(ka0.w), q[7],  p0);
        p0 = fmaf(bflo(kc0.x), q[8],  p0); p0 = fmaf(bfhi(kc0.x), q[9],  p0);
        p0 = fmaf(bflo(kc0.y), q[10], p0); p0 = fmaf(bfhi(kc0.y), q[11], p0);
        p0 = fmaf(bflo(kc0.z), q[12], p0); p0 = fmaf(bfhi(kc0.z), q[13], p0);
        p0 = fmaf(bflo(kc0.w), q[14], p0); p0 = fmaf(bfhi(kc0.w), q[15], p0);

        float p1;
        p1 = fmaf(bfhi(ka1.x), q[1],  bflo(ka1.x) * q[0]);
        p1 = fmaf(bflo(ka1.y), q[2],  p1); p1 = fmaf(bfhi(ka1.y), q[3],  p1);
        p1 = fmaf(bflo(ka1.z), q[4],  p1); p1 = fmaf(bfhi(ka1.z), q[5],  p1);
        p1 = fmaf(bflo(ka1.w), q[6],  p1); p1 = fmaf(bfhi(ka1.w), q[7],  p1);
        p1 = fmaf(bflo(kc1.x), q[8],  p1); p1 = fmaf(bfhi(kc1.x), q[9],  p1);
        p1 = fmaf(bflo(kc1.y), q[10], p1); p1 = fmaf(bfhi(kc1.y), q[11], p1);
        p1 = fmaf(bflo(kc1.z), q[12], p1); p1 = fmaf(bfhi(kc1.z), q[13], p1);
        p1 = fmaf(bflo(kc1.w), q[14], p1); p1 = fmaf(bfhi(kc1.w), q[15], p1);

        float w0 = __expf(fminf(fmaxf(p0 * 0.25f, -5.f), 5.f));
        float w1 = __expf(fminf(fmaxf(p1 * 0.25f, -5.f), 5.f));
        w0 = act0 ? w0 : 0.f;
        w1 = act1 ? w1 : 0.f;
        zacc += w0 + w1;

        acc[0]  = fmaf(bflo(va0.x), w0, acc[0]);  acc[1]  = fmaf(bfhi(va0.x), w0, acc[1]);
        acc[2]  = fmaf(bflo(va0.y), w0, acc[2]);  acc[3]  = fmaf(bfhi(va0.y), w0, acc[3]);
        acc[4]  = fmaf(bflo(va0.z), w0, acc[4]);  acc[5]  = fmaf(bfhi(va0.z), w0, acc[5]);
        acc[6]  = fmaf(bflo(va0.w), w0, acc[6]);  acc[7]  = fmaf(bfhi(va0.w), w0, acc[7]);
        acc[8]  = fmaf(bflo(vc0.x), w0, acc[8]);  acc[9]  = fmaf(bfhi(vc0.x), w0, acc[9]);
        acc[10] = fmaf(bflo(vc0.y), w0, acc[10]); acc[11] = fmaf(bfhi(vc0.y), w0, acc[11]);
        acc[12] = fmaf(bflo(vc0.z), w0, acc[12]); acc[13] = fmaf(bfhi(vc0.z), w0, acc[13]);
        acc[14] = fmaf(bflo(vc0.w), w0, acc[14]); acc[15] = fmaf(bfhi(vc0.w), w0, acc[15]);

        acc[0]  = fmaf(bflo(va1.x), w1, acc[0]);  acc[1]  = fmaf(bfhi(va1.x), w1, acc[1]);
        acc[2]  = fmaf(bflo(va1.y), w1, acc[2]);  acc[3]  = fmaf(bfhi(va1.y), w1, acc[3]);
        acc[4]  = fmaf(bflo(va1.z), w1, acc[4]);  acc[5]  = fmaf(bfhi(va1.z), w1, acc[5]);
        acc[6]  = fmaf(bflo(va1.w), w1, acc[6]);  acc[7]  = fmaf(bfhi(va1.w), w1, acc[7]);
        acc[8]  = fmaf(bflo(vc1.x), w1, acc[8]);  acc[9]  = fmaf(bfhi(vc1.x), w1, acc[9]);
        acc[10] = fmaf(bflo(vc1.y), w1, acc[10]); acc[11] = fmaf(bfhi(vc1.y), w1, acc[11]);
        acc[12] = fmaf(bflo(vc1.z), w1, acc[12]); acc[13] = fmaf(bfhi(vc1.z), w1, acc[13]);
        acc[14] = fmaf(bflo(vc1.w), w1, acc[14]); acc[15] = fmaf(bfhi(vc1.w), w1, acc[15]);
    }

    // reduce across edge slots (lanes differing in bits 3..5)
#pragma unroll
    for (int st = 8; st < 64; st <<= 1) {
        zacc += __shfl_xor(zacc, st);
#pragma unroll
        for (int j = 0; j < 16; ++j) acc[j] += __shfl_xor(acc[j], st);
    }

    if (eo == 0) {
        const float inv = 1.0f / zacc;
        float* op = out + (size_t)n * 128 + h * 16;
        *(float4*)(op)      = make_float4(acc[0]*inv,  acc[1]*inv,  acc[2]*inv,  acc[3]*inv);
        *(float4*)(op + 4)  = make_float4(acc[4]*inv,  acc[5]*inv,  acc[6]*inv,  acc[7]*inv);
        *(float4*)(op + 8)  = make_float4(acc[8]*inv,  acc[9]*inv,  acc[10]*inv, acc[11]*inv);
        *(float4*)(op + 12) = make_float4(acc[12]*inv, acc[13]*inv, acc[14]*inv, acc[15]*inv);
    }
}

extern "C" void kernel_launch(void* const* d_in, const int* in_sizes, int n_in,
                              void* d_out, int out_size, void* d_ws, size_t ws_size,
                              hipStream_t stream)
{
    const float* state = (const float*)d_in[0];
    const int*   src   = (const int*)d_in[1];
    const int*   dst   = (const int*)d_in[2];
    const float* WQ    = (const float*)d_in[3];
    const float* bQ    = (const float*)d_in[4];
    const float* WK    = (const float*)d_in[5];
    const float* bK    = (const float*)d_in[6];
    const float* WV    = (const float*)d_in[7];
    const float* bV    = (const float*)d_in[8];
    float* out = (float*)d_out;

    unsigned short* Qb  = (unsigned short*)d_ws;                 // 12.8 MB
    unsigned short* KVb = Qb + (size_t)NNODES * 128;             // 25.6 MB
    unsigned short* WT  = KVb + (size_t)NNODES * 256;            // 96 KB
    int* dbuf  = (int*)(WT + 3 * 16384);                         // NB*BCAP*4B
    int* sbuf  = dbuf + (size_t)NB * BCAP;
    int* eidx  = sbuf + (size_t)NB * BCAP;
    int* gcur  = eidx + (size_t)NB * BCAP;                       // 256
    int2* offs2 = (int2*)(gcur + 256);                           // 50000 int2

    cast_wt<<<3 * 128, 128, 0, stream>>>(WQ, WK, WV, WT, gcur);
    proj_mfma<<<(NNODES + 63) / 64, 256, 0, stream>>>(state, WT, bQ, bK, bV, Qb, KVb);

    bucket_pass1<<<(NEDGES + 2047) / 2048, 256, 0, stream>>>(src, dst, gcur, dbuf, sbuf);
    bucket_pass2<<<NB, 256, 0, stream>>>(dbuf, sbuf, gcur, eidx, offs2);

    aggregate_kernel<<<(NNODES + 3) / 4, 256, 0, stream>>>(eidx, offs2, Qb, KVb, out);
}